// Round 1
// baseline (399.666 us; speedup 1.0000x reference)
//
#include <hip/hip_runtime.h>

#define NTOK 1024
#define CDIM 1024
#define CRDIM 256
#define ENUM 8
#define IDIM 4096
#define WSTRIDE 4194304ull  // C*I elements per expert weight matrix

typedef __bf16 bf16x8 __attribute__((ext_vector_type(8)));
typedef float f32x4 __attribute__((ext_vector_type(4)));

__device__ __forceinline__ unsigned short f2bf(float f) {
  union { float f; unsigned int u; } v; v.f = f;
  unsigned int r = v.u + 0x7FFFu + ((v.u >> 16) & 1u);  // RNE
  return (unsigned short)(r >> 16);
}

// ---------------- init + cast x to bf16, zero out ----------------
__global__ __launch_bounds__(256) void init_cast_kernel(
    const float* __restrict__ x, unsigned short* __restrict__ xb,
    float* __restrict__ out) {
  int t = blockIdx.x * 256 + threadIdx.x;  // 262144 threads, 4 elems each
  float4 v = reinterpret_cast<const float4*>(x)[t];
  ushort4 o;
  o.x = f2bf(v.x); o.y = f2bf(v.y); o.z = f2bf(v.z); o.w = f2bf(v.w);
  reinterpret_cast<ushort4*>(xb)[t] = o;
  float4 z; z.x = 0.f; z.y = 0.f; z.z = 0.f; z.w = 0.f;
  reinterpret_cast<float4*>(out)[t] = z;
}

// ---------------- router: gates + top-2 ----------------
#define RT 8  // tokens per block
__global__ __launch_bounds__(256) void router_kernel(
    const float* __restrict__ x, const float* __restrict__ Wr1,
    const float* __restrict__ br1, const float* __restrict__ Wr2,
    const float* __restrict__ br2, int* __restrict__ ti,
    float* __restrict__ tw) {
  __shared__ float xs[RT][CDIM];
  __shared__ float hs[RT][CRDIM];
  __shared__ float lg[RT][ENUM];
  const int tid = threadIdx.x;
  const int tok0 = blockIdx.x * RT;
  for (int r = 0; r < RT; ++r) {
    float4 v = reinterpret_cast<const float4*>(x + (size_t)(tok0 + r) * CDIM)[tid];
    *reinterpret_cast<float4*>(&xs[r][tid * 4]) = v;
  }
  __syncthreads();
  float acc[RT];
#pragma unroll
  for (int r = 0; r < RT; ++r) acc[r] = 0.f;
  const int j = tid;
  for (int i = 0; i < CDIM; ++i) {
    float w = Wr1[(size_t)i * CRDIM + j];
#pragma unroll
    for (int r = 0; r < RT; ++r) acc[r] += xs[r][i] * w;
  }
  float b = br1[j];
#pragma unroll
  for (int r = 0; r < RT; ++r) hs[r][j] = fmaxf(acc[r] + b, 0.f);
  __syncthreads();
  if (tid < RT * ENUM) {
    int r = tid >> 3, e = tid & 7;
    float a = 0.f;
    for (int i = 0; i < CRDIM; ++i) a += hs[r][i] * Wr2[(size_t)i * ENUM + e];
    lg[r][e] = a + br2[e];
  }
  __syncthreads();
  if (tid < RT) {
    int r = tid;
    float m = lg[r][0];
#pragma unroll
    for (int e = 1; e < 8; ++e) m = fmaxf(m, lg[r][e]);
    float s = 0.f, g[8];
#pragma unroll
    for (int e = 0; e < 8; ++e) { g[e] = expf(lg[r][e] - m); s += g[e]; }
    float inv = 1.f / s;
    int i0 = 0; float g0 = -1.f;
#pragma unroll
    for (int e = 0; e < 8; ++e) { float ge = g[e] * inv; if (ge > g0) { g0 = ge; i0 = e; } }
    int i1 = 0; float g1 = -2.f;
#pragma unroll
    for (int e = 0; e < 8; ++e) { float ge = g[e] * inv; if (e != i0 && ge > g1) { g1 = ge; i1 = e; } }
    float w0 = 1.f / (1.f + expf((g1 - g0) * 0.5f));  // softmax([g0/2, g1/2])
    int n = tok0 + r;
    ti[2 * n] = i0; ti[2 * n + 1] = i1;
    tw[2 * n] = w0; tw[2 * n + 1] = 1.f - w0;
  }
}

// ---------------- per-expert token lists (stable order) ----------------
__global__ __launch_bounds__(1024) void build_lists_kernel(
    const int* __restrict__ ti, const float* __restrict__ tw,
    int* __restrict__ cnt, int* __restrict__ list, float* __restrict__ gw) {
  __shared__ int s[NTOK];
  const int e = blockIdx.x, n = threadIdx.x;
  int a = ti[2 * n], b = ti[2 * n + 1];
  float w = (a == e) ? tw[2 * n] : ((b == e) ? tw[2 * n + 1] : 0.f);
  int flag = (a == e || b == e) ? 1 : 0;
  s[n] = flag;
  __syncthreads();
  for (int off = 1; off < NTOK; off <<= 1) {
    int v = (n >= off) ? s[n - off] : 0;
    __syncthreads();
    s[n] += v;
    __syncthreads();
  }
  if (flag) { int pos = s[n] - 1; list[e * NTOK + pos] = n; gw[e * NTOK + pos] = w; }
  if (n == NTOK - 1) cnt[e] = s[n];
}

__global__ void offsets_kernel(const int* __restrict__ cnt, int* __restrict__ offs) {
  if (threadIdx.x == 0) {
    int o = 0;
    for (int e = 0; e < 8; ++e) { offs[e] = o; o += cnt[e]; }
    offs[8] = o;
  }
}

// ---------------- fused expert GEMMs ----------------
// MODE 0: H[row] = silu(Xg @ W1 + b1)       (bf16 store to ws)
// MODE 1: out[tok] += gate * (H @ W2 + b2)  (f32 atomic add)
template <int MODE>
__global__ __launch_bounds__(256) void moe_gemm(
    const unsigned short* __restrict__ Abase, const float* __restrict__ Wr,
    const float* __restrict__ Wsh, const float* __restrict__ br,
    const float* __restrict__ bsh, const int* __restrict__ cnt,
    const int* __restrict__ offs, const int* __restrict__ list,
    const float* __restrict__ gw, unsigned short* __restrict__ Hout,
    float* __restrict__ out) {
  constexpr int KD = (MODE == 0) ? CDIM : IDIM;
  constexpr int ND = (MODE == 0) ? IDIM : CDIM;
  const int nt = blockIdx.x, mt = blockIdx.y, e = blockIdx.z;
  const int me = (e < 8) ? cnt[e] : NTOK;
  const int row0 = mt * 128;
  if (row0 >= me) return;
  const int valid = min(128, me - row0);
  const int n0 = nt * 128;
  const float* Bsrc = (e < 8) ? (Wr + (size_t)e * WSTRIDE) : Wsh;
  const float* bias = (e < 8) ? (br + (size_t)e * ND) : bsh;
  const int hbase = (e < 8) ? offs[e] : 2048;
  const int tid = threadIdx.x;

  __shared__ unsigned short sA[128][40];  // [row][k] padded
  __shared__ unsigned short sB[128][40];  // [col][k] transposed, padded
  __shared__ int rowSrc[128];
  __shared__ int sTok[128];
  __shared__ float sGate[128];

  if (tid < 128) {
    int i = tid, ic = min(i, valid - 1);
    if (MODE == 0) {
      rowSrc[i] = (e < 8) ? list[e * NTOK + row0 + ic] : (row0 + ic);
    } else {
      rowSrc[i] = hbase + row0 + i;
      if (e < 8) {
        sTok[i] = list[e * NTOK + row0 + ic];
        sGate[i] = (i < valid) ? gw[e * NTOK + row0 + i] : 0.f;
      }
    }
  }

  f32x4 acc[4][4];
#pragma unroll
  for (int m = 0; m < 4; ++m)
#pragma unroll
    for (int n = 0; n < 4; ++n) acc[m][n] = (f32x4)0.f;

  const int lane = tid & 63;
  const int wv = tid >> 6;
  const int wr = (wv >> 1) * 64, wc = (wv & 1) * 64;
  const int lr = lane & 15, lk = (lane >> 4) * 8;
  const int nnB = tid & 127, kgB = tid >> 7;
  const int rowA = tid >> 2, kgA = (tid & 3) * 8;
  __syncthreads();

  for (int k0 = 0; k0 < KD; k0 += 32) {
    // stage A (bf16 global -> LDS)
    {
      const unsigned short* s0 = Abase + (size_t)rowSrc[rowA] * KD + k0 + kgA;
      *reinterpret_cast<uint4*>(&sA[rowA][kgA]) = *reinterpret_cast<const uint4*>(s0);
      const unsigned short* s1 = Abase + (size_t)rowSrc[rowA + 64] * KD + k0 + kgA;
      *reinterpret_cast<uint4*>(&sA[rowA + 64][kgA]) = *reinterpret_cast<const uint4*>(s1);
    }
    // stage B transposed (f32 global -> bf16 LDS)
    {
      const float* Bp = Bsrc + (size_t)k0 * ND + n0 + nnB;
#pragma unroll
      for (int it = 0; it < 4; ++it) {
        int kb = (it * 2 + kgB) * 4;
        float f0 = Bp[(size_t)(kb + 0) * ND];
        float f1 = Bp[(size_t)(kb + 1) * ND];
        float f2 = Bp[(size_t)(kb + 2) * ND];
        float f3 = Bp[(size_t)(kb + 3) * ND];
        ushort4 o;
        o.x = f2bf(f0); o.y = f2bf(f1); o.z = f2bf(f2); o.w = f2bf(f3);
        *reinterpret_cast<ushort4*>(&sB[nnB][kb]) = o;
      }
    }
    __syncthreads();
    bf16x8 av[4], bv[4];
#pragma unroll
    for (int m = 0; m < 4; ++m)
      av[m] = *reinterpret_cast<const bf16x8*>(&sA[wr + m * 16 + lr][lk]);
#pragma unroll
    for (int n = 0; n < 4; ++n)
      bv[n] = *reinterpret_cast<const bf16x8*>(&sB[wc + n * 16 + lr][lk]);
#pragma unroll
    for (int m = 0; m < 4; ++m)
#pragma unroll
      for (int n = 0; n < 4; ++n)
        acc[m][n] = __builtin_amdgcn_mfma_f32_16x16x32_bf16(av[m], bv[n], acc[m][n], 0, 0, 0);
    __syncthreads();
  }

  const int rbase = wr + ((lane >> 4) << 2);
#pragma unroll
  for (int n = 0; n < 4; ++n) {
    const int col = n0 + wc + n * 16 + lr;
    const float bval = bias[col];
#pragma unroll
    for (int m = 0; m < 4; ++m) {
#pragma unroll
      for (int r = 0; r < 4; ++r) {
        const int i = rbase + m * 16 + r;
        if (i < valid) {
          float v = acc[m][n][r] + bval;
          if (MODE == 0) {
            float sv = v / (1.f + __expf(-v));
            Hout[(size_t)(hbase + row0 + i) * IDIM + col] = f2bf(sv);
          } else {
            if (e < 8)
              atomicAdd(&out[(size_t)sTok[i] * CDIM + col], sGate[i] * v);
            else
              atomicAdd(&out[(size_t)(row0 + i) * CDIM + col], v);
          }
        }
      }
    }
  }
}

extern "C" void kernel_launch(void* const* d_in, const int* in_sizes, int n_in,
                              void* d_out, int out_size, void* d_ws, size_t ws_size,
                              hipStream_t stream) {
  const float* x = (const float*)d_in[0];
  const float* Wr1 = (const float*)d_in[1];
  const float* br1 = (const float*)d_in[2];
  const float* Wr2 = (const float*)d_in[3];
  const float* br2 = (const float*)d_in[4];
  const float* Ws1 = (const float*)d_in[5];
  const float* bs1 = (const float*)d_in[6];
  const float* Ws2 = (const float*)d_in[7];
  const float* bs2 = (const float*)d_in[8];
  const float* We1 = (const float*)d_in[9];
  const float* be1 = (const float*)d_in[10];
  const float* We2 = (const float*)d_in[11];
  const float* be2 = (const float*)d_in[12];
  float* out = (float*)d_out;

  char* ws = (char*)d_ws;
  unsigned short* xb = (unsigned short*)(ws + 0);            // 2 MB
  int* ti = (int*)(ws + 2097152);                            // 8 KB
  float* tw = (float*)(ws + 2105344);                        // 8 KB
  int* cnt = (int*)(ws + 2113536);
  int* offs = (int*)(ws + 2113792);
  int* list = (int*)(ws + 2114048);                          // 32 KB
  float* gw = (float*)(ws + 2146816);                        // 32 KB
  unsigned short* H = (unsigned short*)(ws + 2179584);       // 24 MB (3072 x 4096 bf16)

  init_cast_kernel<<<1024, 256, 0, stream>>>(x, xb, out);
  router_kernel<<<NTOK / RT, 256, 0, stream>>>(x, Wr1, br1, Wr2, br2, ti, tw);
  build_lists_kernel<<<8, 1024, 0, stream>>>(ti, tw, cnt, list, gw);
  offsets_kernel<<<1, 64, 0, stream>>>(cnt, offs);
  moe_gemm<0><<<dim3(32, 8, 9), 256, 0, stream>>>(xb, We1, Ws1, be1, bs1, cnt, offs, list, gw, H, out);
  moe_gemm<1><<<dim3(8, 8, 9), 256, 0, stream>>>(H, We2, Ws2, be2, bs2, cnt, offs, list, gw, nullptr, out);
}

// Round 2
// 336.169 us; speedup vs baseline: 1.1889x; 1.1889x over previous
//
#include <hip/hip_runtime.h>

#define NTOK 1024
#define CDIM 1024
#define CRDIM 256
#define ENUM 8
#define IDIM 4096
#define WSTRIDE 4194304ull  // C*I elements per expert weight matrix
#define SBPAD 56            // LDS row stride in ushorts (112 B)

typedef __bf16 bf16x8 __attribute__((ext_vector_type(8)));
typedef float f32x4 __attribute__((ext_vector_type(4)));

__device__ __forceinline__ unsigned short f2bf(float f) {
  union { float f; unsigned int u; } v; v.f = f;
  unsigned int r = v.u + 0x7FFFu + ((v.u >> 16) & 1u);  // RNE
  return (unsigned short)(r >> 16);
}

// ---------------- init + cast x to bf16, zero out ----------------
__global__ __launch_bounds__(256) void init_cast_kernel(
    const float* __restrict__ x, unsigned short* __restrict__ xb,
    float* __restrict__ out) {
  int t = blockIdx.x * 256 + threadIdx.x;  // 262144 threads, 4 elems each
  float4 v = reinterpret_cast<const float4*>(x)[t];
  ushort4 o;
  o.x = f2bf(v.x); o.y = f2bf(v.y); o.z = f2bf(v.z); o.w = f2bf(v.w);
  reinterpret_cast<ushort4*>(xb)[t] = o;
  float4 z; z.x = 0.f; z.y = 0.f; z.z = 0.f; z.w = 0.f;
  reinterpret_cast<float4*>(out)[t] = z;
}

// ---------------- router: gates + top-2 ----------------
#define RT 8  // tokens per block
__global__ __launch_bounds__(256) void router_kernel(
    const float* __restrict__ x, const float* __restrict__ Wr1,
    const float* __restrict__ br1, const float* __restrict__ Wr2,
    const float* __restrict__ br2, int* __restrict__ ti,
    float* __restrict__ tw) {
  __shared__ float xs[RT][CDIM];
  __shared__ float hs[RT][CRDIM];
  __shared__ float lg[RT][ENUM];
  const int tid = threadIdx.x;
  const int tok0 = blockIdx.x * RT;
  for (int r = 0; r < RT; ++r) {
    float4 v = reinterpret_cast<const float4*>(x + (size_t)(tok0 + r) * CDIM)[tid];
    *reinterpret_cast<float4*>(&xs[r][tid * 4]) = v;
  }
  __syncthreads();
  float acc[RT];
#pragma unroll
  for (int r = 0; r < RT; ++r) acc[r] = 0.f;
  const int j = tid;
  for (int i = 0; i < CDIM; ++i) {
    float w = Wr1[(size_t)i * CRDIM + j];
#pragma unroll
    for (int r = 0; r < RT; ++r) acc[r] += xs[r][i] * w;
  }
  float b = br1[j];
#pragma unroll
  for (int r = 0; r < RT; ++r) hs[r][j] = fmaxf(acc[r] + b, 0.f);
  __syncthreads();
  if (tid < RT * ENUM) {
    int r = tid >> 3, e = tid & 7;
    float a = 0.f;
    for (int i = 0; i < CRDIM; ++i) a += hs[r][i] * Wr2[(size_t)i * ENUM + e];
    lg[r][e] = a + br2[e];
  }
  __syncthreads();
  if (tid < RT) {
    int r = tid;
    float m = lg[r][0];
#pragma unroll
    for (int e = 1; e < 8; ++e) m = fmaxf(m, lg[r][e]);
    float s = 0.f, g[8];
#pragma unroll
    for (int e = 0; e < 8; ++e) { g[e] = expf(lg[r][e] - m); s += g[e]; }
    float inv = 1.f / s;
    int i0 = 0; float g0 = -1.f;
#pragma unroll
    for (int e = 0; e < 8; ++e) { float ge = g[e] * inv; if (ge > g0) { g0 = ge; i0 = e; } }
    int i1 = 0; float g1 = -2.f;
#pragma unroll
    for (int e = 0; e < 8; ++e) { float ge = g[e] * inv; if (e != i0 && ge > g1) { g1 = ge; i1 = e; } }
    float w0 = 1.f / (1.f + expf((g1 - g0) * 0.5f));  // softmax([g0/2, g1/2])
    int n = tok0 + r;
    ti[2 * n] = i0; ti[2 * n + 1] = i1;
    tw[2 * n] = w0; tw[2 * n + 1] = 1.f - w0;
  }
}

// ---------------- per-expert token lists (stable order) ----------------
__global__ __launch_bounds__(1024) void build_lists_kernel(
    const int* __restrict__ ti, const float* __restrict__ tw,
    int* __restrict__ cnt, int* __restrict__ list, float* __restrict__ gw) {
  __shared__ int s[NTOK];
  const int e = blockIdx.x, n = threadIdx.x;
  int a = ti[2 * n], b = ti[2 * n + 1];
  float w = (a == e) ? tw[2 * n] : ((b == e) ? tw[2 * n + 1] : 0.f);
  int flag = (a == e || b == e) ? 1 : 0;
  s[n] = flag;
  __syncthreads();
  for (int off = 1; off < NTOK; off <<= 1) {
    int v = (n >= off) ? s[n - off] : 0;
    __syncthreads();
    s[n] += v;
    __syncthreads();
  }
  if (flag) { int pos = s[n] - 1; list[e * NTOK + pos] = n; gw[e * NTOK + pos] = w; }
  if (n == NTOK - 1) cnt[e] = s[n];
}

__global__ void offsets_kernel(const int* __restrict__ cnt, int* __restrict__ offs) {
  if (threadIdx.x == 0) {
    int o = 0;
    for (int e = 0; e < 8; ++e) { offs[e] = o; o += cnt[e]; }
    offs[8] = o;
  }
}

// ---------------- fused expert GEMMs ----------------
// MODE 0: H[row] = silu(Xg @ W1 + b1)       (bf16 store to ws)
// MODE 1: out[tok] += gate * (H @ W2 + b2)  (f32 atomic add, split-K=4)
template <int MODE>
__global__ __launch_bounds__(256) void moe_gemm(
    const unsigned short* __restrict__ Abase, const float* __restrict__ Wr,
    const float* __restrict__ Wsh, const float* __restrict__ br,
    const float* __restrict__ bsh, const int* __restrict__ cnt,
    const int* __restrict__ offs, const int* __restrict__ list,
    const float* __restrict__ gw, unsigned short* __restrict__ Hout,
    float* __restrict__ out) {
  constexpr int KD = (MODE == 0) ? CDIM : IDIM;
  constexpr int ND = (MODE == 0) ? IDIM : CDIM;
  constexpr int KCH = (MODE == 0) ? KD : (KD / 4);  // K-chunk per block
  const int nt = blockIdx.x, mt = blockIdx.y;
  const int e = (MODE == 0) ? blockIdx.z : (blockIdx.z % 9);
  const int kc = (MODE == 0) ? 0 : (blockIdx.z / 9);
  const int me = (e < 8) ? cnt[e] : NTOK;
  const int row0 = mt * 128;
  if (row0 >= me) return;
  const int valid = min(128, me - row0);
  const int n0 = nt * 128;
  const float* Bsrc = (e < 8) ? (Wr + (size_t)e * WSTRIDE) : Wsh;
  const float* bias = (e < 8) ? (br + (size_t)e * ND) : bsh;
  const int hbase = (e < 8) ? offs[e] : 2048;
  const int tid = threadIdx.x;

  __shared__ __align__(16) unsigned short sA[128][SBPAD];  // [row][k]
  __shared__ __align__(16) unsigned short sB[128][SBPAD];  // [col][k] transposed
  __shared__ int rowSrc[128];
  __shared__ int sTok[128];
  __shared__ float sGate[128];

  if (tid < 128) {
    int i = tid, ic = min(i, valid - 1);
    if (MODE == 0) {
      rowSrc[i] = (e < 8) ? list[e * NTOK + row0 + ic] : (row0 + ic);
    } else {
      rowSrc[i] = hbase + row0 + i;
      if (e < 8) {
        sTok[i] = list[e * NTOK + row0 + ic];
        sGate[i] = (i < valid) ? gw[e * NTOK + row0 + i] : 0.f;
      }
    }
  }

  f32x4 acc[4][4];
#pragma unroll
  for (int m = 0; m < 4; ++m)
#pragma unroll
    for (int n = 0; n < 4; ++n) acc[m][n] = (f32x4)0.f;

  const int lane = tid & 63;
  const int wv = tid >> 6;
  const int wr = (wv >> 1) * 64, wc = (wv & 1) * 64;
  const int lr = lane & 15, lk = (lane >> 4) * 8;
  const int rowA = tid >> 2, kgA = (tid & 3) * 8;   // A: 16B per thread
  const int ncB = (tid & 63) * 2, kpB = tid >> 6;   // B: 2 cols x 8 k per thread
  __syncthreads();  // rowSrc ready before first prefetch

  const int kbeg = kc * KCH, kend = kbeg + KCH;
  uint4 pa0, pa1;
  float2 pb[8];

#define LOADTILE(K0)                                                            \
  {                                                                             \
    pa0 = *reinterpret_cast<const uint4*>(Abase + (size_t)rowSrc[rowA] * KD + (K0) + kgA);      \
    pa1 = *reinterpret_cast<const uint4*>(Abase + (size_t)rowSrc[rowA + 64] * KD + (K0) + kgA); \
    const float* Bp = Bsrc + (size_t)((K0) + kpB * 8) * ND + n0 + ncB;          \
    _Pragma("unroll") for (int j = 0; j < 8; ++j)                               \
        pb[j] = *reinterpret_cast<const float2*>(Bp + (size_t)j * ND);          \
  }

  LOADTILE(kbeg);
  for (int k0 = kbeg; k0 < kend; k0 += 32) {
    __syncthreads();  // previous MFMA done; LDS writable
    *reinterpret_cast<uint4*>(&sA[rowA][kgA]) = pa0;
    *reinterpret_cast<uint4*>(&sA[rowA + 64][kgA]) = pa1;
    {
      bf16x8 q0, q1;
#pragma unroll
      for (int j = 0; j < 8; ++j) { q0[j] = (__bf16)pb[j].x; q1[j] = (__bf16)pb[j].y; }
      *reinterpret_cast<bf16x8*>(&sB[ncB][kpB * 8]) = q0;
      *reinterpret_cast<bf16x8*>(&sB[ncB + 1][kpB * 8]) = q1;
    }
    __syncthreads();  // LDS ready
    if (k0 + 32 < kend) LOADTILE(k0 + 32);  // prefetch next while MFMA runs
    bf16x8 av[4], bv[4];
#pragma unroll
    for (int m = 0; m < 4; ++m)
      av[m] = *reinterpret_cast<const bf16x8*>(&sA[wr + m * 16 + lr][lk]);
#pragma unroll
    for (int n = 0; n < 4; ++n)
      bv[n] = *reinterpret_cast<const bf16x8*>(&sB[wc + n * 16 + lr][lk]);
#pragma unroll
    for (int m = 0; m < 4; ++m)
#pragma unroll
      for (int n = 0; n < 4; ++n)
        acc[m][n] = __builtin_amdgcn_mfma_f32_16x16x32_bf16(av[m], bv[n], acc[m][n], 0, 0, 0);
  }
#undef LOADTILE

  const int rbase = wr + ((lane >> 4) << 2);
#pragma unroll
  for (int n = 0; n < 4; ++n) {
    const int col = n0 + wc + n * 16 + lr;
    const float bval = (MODE == 0 || kc == 0) ? bias[col] : 0.f;
#pragma unroll
    for (int m = 0; m < 4; ++m) {
#pragma unroll
      for (int r = 0; r < 4; ++r) {
        const int i = rbase + m * 16 + r;
        if (i < valid) {
          float v = acc[m][n][r] + bval;
          if (MODE == 0) {
            float sv = v / (1.f + __expf(-v));
            Hout[(size_t)(hbase + row0 + i) * IDIM + col] = f2bf(sv);
          } else {
            if (e < 8)
              atomicAdd(&out[(size_t)sTok[i] * CDIM + col], sGate[i] * v);
            else
              atomicAdd(&out[(size_t)(row0 + i) * CDIM + col], v);
          }
        }
      }
    }
  }
}

extern "C" void kernel_launch(void* const* d_in, const int* in_sizes, int n_in,
                              void* d_out, int out_size, void* d_ws, size_t ws_size,
                              hipStream_t stream) {
  const float* x = (const float*)d_in[0];
  const float* Wr1 = (const float*)d_in[1];
  const float* br1 = (const float*)d_in[2];
  const float* Wr2 = (const float*)d_in[3];
  const float* br2 = (const float*)d_in[4];
  const float* Ws1 = (const float*)d_in[5];
  const float* bs1 = (const float*)d_in[6];
  const float* Ws2 = (const float*)d_in[7];
  const float* bs2 = (const float*)d_in[8];
  const float* We1 = (const float*)d_in[9];
  const float* be1 = (const float*)d_in[10];
  const float* We2 = (const float*)d_in[11];
  const float* be2 = (const float*)d_in[12];
  float* out = (float*)d_out;

  char* ws = (char*)d_ws;
  unsigned short* xb = (unsigned short*)(ws + 0);            // 2 MB
  int* ti = (int*)(ws + 2097152);                            // 8 KB
  float* tw = (float*)(ws + 2105344);                        // 8 KB
  int* cnt = (int*)(ws + 2113536);
  int* offs = (int*)(ws + 2113792);
  int* list = (int*)(ws + 2114048);                          // 32 KB
  float* gw = (float*)(ws + 2146816);                        // 32 KB
  unsigned short* H = (unsigned short*)(ws + 2179584);       // 24 MB (3072 x 4096 bf16)

  init_cast_kernel<<<1024, 256, 0, stream>>>(x, xb, out);
  router_kernel<<<NTOK / RT, 256, 0, stream>>>(x, Wr1, br1, Wr2, br2, ti, tw);
  build_lists_kernel<<<8, 1024, 0, stream>>>(ti, tw, cnt, list, gw);
  offsets_kernel<<<1, 64, 0, stream>>>(cnt, offs);
  moe_gemm<0><<<dim3(32, 8, 9), 256, 0, stream>>>(xb, We1, Ws1, be1, bs1, cnt, offs, list, gw, H, out);
  moe_gemm<1><<<dim3(8, 8, 36), 256, 0, stream>>>(H, We2, Ws2, be2, bs2, cnt, offs, list, gw, nullptr, out);
}